// Round 5
// baseline (406.201 us; speedup 1.0000x reference)
//
#include <hip/hip_runtime.h>

// ---------------- Diagnostic marker: neither input mapping validated ----------------
__global__ void bad_map_marker(float* out) {
    if (threadIdx.x == 0 && blockIdx.x == 0) out[0] = 1.0e6f;
}

// ---------------- Tail (generic fallback only): LN1+ReLU -> L2 -> LN2+ReLU -> L3 ----------------
__device__ __forceinline__ void mlp_tail_compute(float* h, float* pr, int D,
        const float* g1, const float* be1,
        const float* W2, const float* b2,
        const float* g2, const float* be2,
        const float* W3, const float* b3) {
    float s = 0.f, ss = 0.f;
    #pragma unroll
    for (int d = 0; d < 64; ++d) { s += h[d]; ss += h[d] * h[d]; }
    float mu  = s * (1.f / 64.f);
    float inv = rsqrtf(ss * (1.f / 64.f) - mu * mu + 1e-5f);
    #pragma unroll
    for (int d = 0; d < 64; ++d)
        h[d] = fmaxf((h[d] - mu) * inv * g1[d] + be1[d], 0.f);

    float a2[32];
    const float4* w2v = (const float4*)W2;
    #pragma unroll
    for (int n = 0; n < 32; ++n) a2[n] = b2[n];
    for (int k = 0; k < 64; ++k) {
        float hk = h[k];
        #pragma unroll
        for (int q = 0; q < 8; ++q) {
            float4 w = w2v[k * 8 + q];
            a2[4 * q + 0] += hk * w.x;
            a2[4 * q + 1] += hk * w.y;
            a2[4 * q + 2] += hk * w.z;
            a2[4 * q + 3] += hk * w.w;
        }
    }
    s = 0.f; ss = 0.f;
    #pragma unroll
    for (int n = 0; n < 32; ++n) { s += a2[n]; ss += a2[n] * a2[n]; }
    mu  = s * (1.f / 32.f);
    inv = rsqrtf(ss * (1.f / 32.f) - mu * mu + 1e-5f);
    #pragma unroll
    for (int n = 0; n < 32; ++n)
        a2[n] = fmaxf((a2[n] - mu) * inv * g2[n] + be2[n], 0.f);

    for (int d = 0; d < D; ++d) pr[d] = b3[d];
    for (int k = 0; k < 32; ++k) {
        float hk = a2[k];
        const float* wr = W3 + k * D;
        for (int d = 0; d < D; ++d) pr[d] += hk * wr[d];
    }
}

// Coalesced diag-embed epilogue (generic path), 256 pairs/block.
__device__ __forceinline__ void store_diag16_f32_256(const float* pp, float* out, int P) {
    const int t = threadIdx.x;
    float4* outv = (float4*)out + (size_t)blockIdx.x * 16384;
    const int pbase = blockIdx.x * 256;
    #pragma unroll 8
    for (int it = 0; it < 64; ++it) {
        int g = it * 256 + t;
        int pl = g >> 6;
        int rem = g & 63;
        int d = rem >> 2;
        int c4 = rem & 3;
        float val = pp[pl * 17 + d];
        bool on = (d >> 2) == c4;
        float4 v;
        v.x = (on && (d & 3) == 0) ? val : 0.f;
        v.y = (on && (d & 3) == 1) ? val : 0.f;
        v.z = (on && (d & 3) == 2) ? val : 0.f;
        v.w = (on && (d & 3) == 3) ? val : 0.f;
        if (pbase + pl < P) outv[g] = v;
    }
}

// ---------------- Fast path stage 1 (F==128): tiled GEMM, Y[e][n] ----------------
// R0 structure (64 edges x 128 cols, thread: 4 edges x 8 cols) — measured-good.
__global__ __launch_bounds__(256)
void precompute_y(const float* __restrict__ ef, const float* __restrict__ W1,
                  const float* __restrict__ b1, float* __restrict__ Y, int E) {
    __shared__ __align__(16) float el[64 * 132];   // 33792 B
    const int t = threadIdx.x;
    const int ebase = blockIdx.x * 64;

    for (int idx = t; idx < 2048; idx += 256) {
        int er = idx >> 5, ec = idx & 31;
        if (ebase + er < E)
            *((float4*)(el + er * 132) + ec) =
                *((const float4*)(ef + (size_t)(ebase + er) * 128) + ec);
    }
    __syncthreads();

    const int cg = t & 15;
    const int eg = t >> 4;
    const int half = cg >> 3;
    const int col64 = (cg & 7) * 8;

    float acc[4][8];
    #pragma unroll
    for (int i = 0; i < 4; ++i)
        #pragma unroll
        for (int c = 0; c < 8; ++c) acc[i][c] = 0.f;

    const float* wbase = W1 + (size_t)half * 128 * 64 + col64;
    #pragma unroll 4
    for (int k = 0; k < 128; ++k) {
        float4 w0 = *(const float4*)(wbase + (size_t)k * 64);
        float4 w1 = *(const float4*)(wbase + (size_t)k * 64 + 4);
        float wv[8] = {w0.x, w0.y, w0.z, w0.w, w1.x, w1.y, w1.z, w1.w};
        #pragma unroll
        for (int i = 0; i < 4; ++i) {
            float a = el[(eg * 4 + i) * 132 + k];
            #pragma unroll
            for (int c = 0; c < 8; ++c) acc[i][c] += a * wv[c];
        }
    }

    float bb[8];
    #pragma unroll
    for (int c = 0; c < 8; ++c) bb[c] = (half == 0) ? b1[col64 + c] : 0.f;
    #pragma unroll
    for (int i = 0; i < 4; ++i) {
        int e = ebase + eg * 4 + i;
        if (e < E) {
            float* dst = Y + (size_t)e * 128 + half * 64 + col64;
            #pragma unroll
            for (int c = 0; c < 8; ++c) dst[c] = acc[i][c] + bb[c];
        }
    }
}

// ---------------- Fast path stage 2: 4 lanes per pair (quad k-split) ----------------
// Occupancy fix: 1-thread/pair held h[64]+a2[32] live (~180 VGPR -> 2 waves/SIMD;
// random Y gathers to L3 cannot be hidden). Quad split holds h[16]/lane, reduces
// LN/GEMV partials with __shfl_xor(1/2) (DPP-speed), targets <=128 VGPR ->
// 4 waves/SIMD. W2 staged TRANSPOSED [32][64] so each lane reads its contiguous
// k-range as float4 (quad lanes 2-way on banks = free).
__global__ __launch_bounds__(256, 4)
void sheaf_pairs_quad(const int* __restrict__ pi, const int* __restrict__ pj,
                      const float* __restrict__ Y,
                      const float* __restrict__ g1, const float* __restrict__ be1,
                      const float* __restrict__ W2, const float* __restrict__ b2,
                      const float* __restrict__ g2, const float* __restrict__ be2,
                      const float* __restrict__ W3, const float* __restrict__ b3,
                      float* __restrict__ out, int P) {
    __shared__ __align__(16) float w2t[32 * 64];   // W2^T [n][k]
    __shared__ __align__(16) float w3s[32 * 16];
    __shared__ __align__(16) float pp[64 * 20];    // params, padded stride 20
    __shared__ float g1s[64], be1s[64], b2s[32], g2s[32], be2s[32], b3s[16];

    const int t  = threadIdx.x;
    const int pl = t >> 2;        // pair within block (0..63)
    const int q  = t & 3;         // sublane within quad
    const int pbase = blockIdx.x * 64;
    int p  = pbase + pl;
    int pc = p < P ? p : P - 1;
    int i = pi[pc], j = pj[pc];

    const int kbase = q * 16;
    const float4* y1 = (const float4*)(Y + (size_t)i * 128 + kbase);
    const float4* y2 = (const float4*)(Y + (size_t)j * 128 + 64 + kbase);
    float4 ya0 = y1[0], ya1 = y1[1], ya2 = y1[2], ya3 = y1[3];
    float4 yb0 = y2[0], yb1 = y2[1], yb2 = y2[2], yb3 = y2[3];

    // Stage weights into LDS (once per block). W2 transposed: LDS writes coalesced,
    // global reads strided but W2 is 8 KB and L1/L2-hot.
    for (int idx = t; idx < 2048; idx += 256) {
        int k = idx & 63, n = idx >> 6;
        w2t[n * 64 + k] = W2[k * 32 + n];
    }
    if (t < 128) ((float4*)w3s)[t] = ((const float4*)W3)[t];
    if (t < 64)                 { g1s[t] = g1[t]; be1s[t] = be1[t]; }
    else if (t < 96)            b2s[t - 64]   = b2[t - 64];
    else if (t < 128)           g2s[t - 96]   = g2[t - 96];
    else if (t < 160)           be2s[t - 128] = be2[t - 128];
    else if (t < 176)           b3s[t - 160]  = b3[t - 160];
    __syncthreads();

    float h[16];
    h[ 0] = ya0.x + yb0.x; h[ 1] = ya0.y + yb0.y; h[ 2] = ya0.z + yb0.z; h[ 3] = ya0.w + yb0.w;
    h[ 4] = ya1.x + yb1.x; h[ 5] = ya1.y + yb1.y; h[ 6] = ya1.z + yb1.z; h[ 7] = ya1.w + yb1.w;
    h[ 8] = ya2.x + yb2.x; h[ 9] = ya2.y + yb2.y; h[10] = ya2.z + yb2.z; h[11] = ya2.w + yb2.w;
    h[12] = ya3.x + yb3.x; h[13] = ya3.y + yb3.y; h[14] = ya3.z + yb3.z; h[15] = ya3.w + yb3.w;

    // LN1 over 64 values: local partial + quad butterfly.
    float s = 0.f, ss = 0.f;
    #pragma unroll
    for (int d = 0; d < 16; ++d) { s += h[d]; ss += h[d] * h[d]; }
    s  += __shfl_xor(s, 1);  ss += __shfl_xor(ss, 1);
    s  += __shfl_xor(s, 2);  ss += __shfl_xor(ss, 2);
    float mu  = s * (1.f / 64.f);
    float inv = rsqrtf(ss * (1.f / 64.f) - mu * mu + 1e-5f);
    #pragma unroll
    for (int d = 0; d < 16; ++d)
        h[d] = fmaxf((h[d] - mu) * inv * g1s[kbase + d] + be1s[kbase + d], 0.f);

    // Linear(64,32): k-partial per lane, then quad reduce.
    float a2[32];
    #pragma unroll
    for (int n = 0; n < 32; ++n) {
        const float4* wr = (const float4*)(w2t + n * 64 + kbase);
        float4 w0 = wr[0], w1 = wr[1], w2f = wr[2], w3f = wr[3];
        a2[n] = h[ 0] * w0.x + h[ 1] * w0.y + h[ 2] * w0.z + h[ 3] * w0.w
              + h[ 4] * w1.x + h[ 5] * w1.y + h[ 6] * w1.z + h[ 7] * w1.w
              + h[ 8] * w2f.x + h[ 9] * w2f.y + h[10] * w2f.z + h[11] * w2f.w
              + h[12] * w3f.x + h[13] * w3f.y + h[14] * w3f.z + h[15] * w3f.w;
    }
    #pragma unroll
    for (int n = 0; n < 32; ++n) {
        a2[n] += __shfl_xor(a2[n], 1);
        a2[n] += __shfl_xor(a2[n], 2);
    }

    // + b2, LN2 + ReLU (all quad lanes hold full a2; redundant but trivial).
    s = 0.f; ss = 0.f;
    #pragma unroll
    for (int n = 0; n < 32; ++n) {
        a2[n] += b2s[n];
        s += a2[n]; ss += a2[n] * a2[n];
    }
    mu  = s * (1.f / 32.f);
    inv = rsqrtf(ss * (1.f / 32.f) - mu * mu + 1e-5f);
    #pragma unroll
    for (int n = 0; n < 32; ++n)
        a2[n] = fmaxf((a2[n] - mu) * inv * g2s[n] + be2s[n], 0.f);

    // Linear(32,16): output-split, lane q computes cols q*4..q*4+3.
    const int n3 = q * 4;
    float pr0 = b3s[n3 + 0], pr1 = b3s[n3 + 1], pr2 = b3s[n3 + 2], pr3 = b3s[n3 + 3];
    #pragma unroll
    for (int k = 0; k < 32; ++k) {
        float4 w = *(const float4*)(w3s + k * 16 + n3);
        float ak = a2[k];
        pr0 += ak * w.x; pr1 += ak * w.y; pr2 += ak * w.z; pr3 += ak * w.w;
    }
    *(float4*)(pp + pl * 20 + n3) = make_float4(pr0, pr1, pr2, pr3);
    __syncthreads();

    // Diag-embed store: 64 pairs x 64 float4 = 4096 chunks, 16/thread, coalesced.
    float4* outv = (float4*)out + (size_t)blockIdx.x * 4096;
    #pragma unroll 4
    for (int it = 0; it < 16; ++it) {
        int g = it * 256 + t;
        int pl2 = g >> 6;
        int rem = g & 63;
        int d = rem >> 2;
        int c4 = rem & 3;
        float val = pp[pl2 * 20 + d];
        bool on = (d >> 2) == c4;
        float4 v;
        v.x = (on && (d & 3) == 0) ? val : 0.f;
        v.y = (on && (d & 3) == 1) ? val : 0.f;
        v.z = (on && (d & 3) == 2) ? val : 0.f;
        v.w = (on && (d & 3) == 3) ? val : 0.f;
        if (pbase + pl2 < P) outv[g] = v;
    }
}

// ---------------- Generic fallback: runtime F, D (<=32) ----------------
__global__ __launch_bounds__(256)
void sheaf_generic(const float* __restrict__ ef,
                   const int* __restrict__ pi, const int* __restrict__ pj,
                   const float* __restrict__ W1, const float* __restrict__ b1,
                   const float* __restrict__ g1, const float* __restrict__ be1,
                   const float* __restrict__ W2, const float* __restrict__ b2,
                   const float* __restrict__ g2, const float* __restrict__ be2,
                   const float* __restrict__ W3, const float* __restrict__ b3,
                   float* __restrict__ out, int P, int F, int D) {
    __shared__ float pp[256 * 17];
    int p = blockIdx.x * 256 + threadIdx.x;
    int pc = p < P ? p : P - 1;
    int i = pi[pc], j = pj[pc];
    const float* efi = ef + (size_t)i * F;
    const float* efj = ef + (size_t)j * F;
    float h[64];
    #pragma unroll
    for (int n = 0; n < 64; ++n) h[n] = b1[n];
    for (int k = 0; k < F; ++k) {
        float ei = efi[k];
        float ej = efj[k];
        const float* wi = W1 + (size_t)k * 64;
        const float* wj = W1 + (size_t)(F + k) * 64;
        #pragma unroll
        for (int n = 0; n < 64; ++n) h[n] += ei * wi[n] + ej * wj[n];
    }
    float pr[32];
    mlp_tail_compute(h, pr, D, g1, be1, W2, b2, g2, be2, W3, b3);

    if (D == 16) {
        #pragma unroll
        for (int d = 0; d < 16; ++d) pp[threadIdx.x * 17 + d] = pr[d];
        __syncthreads();
        store_diag16_f32_256(pp, out, P);
    } else {
        if (p < P) {
            float* po = out + (size_t)p * D * D;
            for (int r = 0; r < D; ++r) {
                float dv = pr[r];
                for (int c = 0; c < D; ++c) po[r * D + c] = (r == c) ? dv : 0.f;
            }
        }
    }
}

// ---------------- Host side: derive ALL dims from in_sizes/out_size ----------------
struct Map { int ef, pi, pj, w1, b1, g1, be1, w2, b2, g2, be2, w3, b3; };

static bool validate_map(const Map& m, const int* s, int n_in, long out_size,
                         int* Fo, int* Eo, int* Do, int* Po) {
    if (n_in < 13) return false;
    if (s[m.b1] != 64 || s[m.g1] != 64 || s[m.be1] != 64) return false;
    if (s[m.b2] != 32 || s[m.g2] != 32 || s[m.be2] != 32) return false;
    if (s[m.w2] != 64 * 32) return false;
    long w1 = s[m.w1];
    if (w1 <= 0 || (w1 % 128) != 0) return false;       // W1 = (2F, 64)
    long F = w1 / 128;
    if (F <= 0) return false;
    int D = s[m.b3];
    if (D <= 0 || D > 32) return false;
    if (s[m.w3] != 32 * D) return false;
    long P = s[m.pi];
    if (P <= 0 || s[m.pj] != P) return false;
    long ef = s[m.ef];
    if (ef <= 0 || (ef % F) != 0) return false;
    long E = ef / F;
    if (out_size != P * D * D) return false;
    *Fo = (int)F; *Eo = (int)E; *Do = D; *Po = (int)P;
    return true;
}

extern "C" void kernel_launch(void* const* d_in, const int* in_sizes, int n_in,
                              void* d_out, int out_size, void* d_ws, size_t ws_size,
                              hipStream_t stream) {
    const Map pos   = {0, 1, 2, 3, 4, 5, 6, 7, 8, 9, 10, 11, 12};
    const Map alpha = {8, 11, 12, 0, 3, 9, 6, 1, 4, 10, 7, 2, 5};

    int F = 0, E = 0, D = 0, P = 0;
    Map m;
    if (validate_map(pos, in_sizes, n_in, (long)out_size, &F, &E, &D, &P)) {
        m = pos;
    } else if (validate_map(alpha, in_sizes, n_in, (long)out_size, &F, &E, &D, &P)) {
        m = alpha;
    } else {
        bad_map_marker<<<dim3(1), dim3(64), 0, stream>>>((float*)d_out);
        return;
    }

    const float* ef  = (const float*)d_in[m.ef];
    const int*   pi  = (const int*)d_in[m.pi];
    const int*   pj  = (const int*)d_in[m.pj];
    const float* W1  = (const float*)d_in[m.w1];
    const float* b1  = (const float*)d_in[m.b1];
    const float* g1  = (const float*)d_in[m.g1];
    const float* be1 = (const float*)d_in[m.be1];
    const float* W2  = (const float*)d_in[m.w2];
    const float* b2  = (const float*)d_in[m.b2];
    const float* g2  = (const float*)d_in[m.g2];
    const float* be2 = (const float*)d_in[m.be2];
    const float* W3  = (const float*)d_in[m.w3];
    const float* b3  = (const float*)d_in[m.b3];
    float* out = (float*)d_out;

    const size_t y_bytes = (size_t)E * 128 * 4;

    if (F == 128 && D == 16 && ws_size >= y_bytes) {
        float* Y = (float*)d_ws;
        precompute_y<<<dim3((E + 63) / 64), dim3(256), 0, stream>>>(ef, W1, b1, Y, E);
        sheaf_pairs_quad<<<dim3((P + 63) / 64), dim3(256), 0, stream>>>(
            pi, pj, Y, g1, be1, W2, b2, g2, be2, W3, b3, out, P);
    } else {
        sheaf_generic<<<dim3((P + 255) / 256), dim3(256), 0, stream>>>(
            ef, pi, pj, W1, b1, g1, be1, W2, b2, g2, be2, W3, b3, out, P, F, D);
    }
}